// Round 4
// baseline (215.592 us; speedup 1.0000x reference)
//
#include <hip/hip_runtime.h>
#include <hip/hip_cooperative_groups.h>

namespace cg = cooperative_groups;

constexpr int NIMG  = 32;
constexpr int W     = 512;
constexpr int S     = 8;                          // row-slices per image
constexpr int WORDS = 32768;                      // 65536 bins packed 2 x u16 per u32
constexpr int WPS   = WORDS / S;                  // 4096 words per phase-2 range
constexpr float SUMQ = 2.0f * 511.0f * 512.0f;    // sum of symmetrized histogram

// ---------------------------------------------------------------------------
// symmetric pair insert into u16-packed LDS histogram
// ---------------------------------------------------------------------------
__device__ __forceinline__ void pair_add(unsigned int* sh, int a, int b) {
    int b1 = (a << 8) | b;
    atomicAdd(&sh[b1 >> 1], 1u << ((b1 & 1) << 4));
    int b2 = (b << 8) | a;
    atomicAdd(&sh[b2 >> 1], 1u << ((b2 & 1) << 4));
}

__device__ __forceinline__ int quant(float v) {
    int q = (int)(v * 256.0f);                    // trunc toward zero == astype(int32)
    return min(255, max(0, q));
}

__device__ __forceinline__ float wave_red(float v) {
#pragma unroll
    for (int off = 32; off; off >>= 1) v += __shfl_down(v, off);
    return v;
}

// ---------------------------------------------------------------------------
// Fused cooperative kernel. Grid = NIMG*S = 256 blocks (1 per CU, 128KB LDS).
//   Phase 1: block (img,s) builds symmetrized slice GLCM Q_s in LDS (u16
//            packed; max per-bin count 2*64*511=65408 < 65536), writes it to
//            an exclusive global region (skipping its own phase-2 range,
//            which stays in LDS), and computes the 6 linear moments fused.
//   Phase 2: after grid.sync, block (img,s) sums words [s*4096,(s+1)*4096)
//            across the image's 8 slices (7 global uint4 + 1 LDS uint4 per
//            thread) and square-sums for energy.
//   Phase 3: after grid.sync, block 0 finalizes (fixed-order, deterministic).
// ---------------------------------------------------------------------------
__global__ void __launch_bounds__(1024)
glcm_fused(const float* __restrict__ x, unsigned int* __restrict__ hist,
           float* __restrict__ moments, float* __restrict__ q2part,
           float* __restrict__ out) {
    __shared__ unsigned int sh[WORDS];
    __shared__ float red[16][6];
    __shared__ float red2[16];

    const int t   = threadIdx.x;
    const int bid = blockIdx.x;
    const int img = bid >> 3;
    const int sl  = bid & 7;
    cg::grid_group grid = cg::this_grid();

    // ---- phase 1: zero LDS (uint4), build slice histogram -----------------
    for (int w4 = t; w4 < WORDS / 4; w4 += 1024)
        reinterpret_cast<uint4*>(sh)[w4] = uint4{0u, 0u, 0u, 0u};
    __syncthreads();

    const int rows = W / S;                       // 64
    const int nf4  = rows * (W / 4);              // 8192 float4s per slice
    const float* __restrict__ xb = x + (size_t)bid * rows * W;

    for (int f = t; f < nf4; f += 1024) {
        float4 v = reinterpret_cast<const float4*>(xb)[f];
        int b0 = quant(v.x);
        int b1 = quant(v.y);
        int b2 = quant(v.z);
        int b3 = quant(v.w);
        pair_add(sh, b0, b1);
        pair_add(sh, b1, b2);
        pair_add(sh, b2, b3);
        if ((f & (W / 4 - 1)) != (W / 4 - 1)) {   // not last float4 of its row
            int b4 = quant(xb[f * 4 + 4]);
            pair_add(sh, b3, b4);
        }
    }
    __syncthreads();

    // ---- write-out (uint4, skip own phase-2 range) + linear moments -------
    unsigned int* __restrict__ hb = hist + (size_t)bid * WORDS;
    float s_con = 0.f, s_dis = 0.f, s_hom = 0.f;
    float s_i = 0.f, s_ii = 0.f, s_ij = 0.f;

    for (int w4 = t; w4 < WORDS / 4; w4 += 1024) {
        uint4 v = reinterpret_cast<uint4*>(sh)[w4];
        if ((w4 >> 10) != sl)                     // own range lives in LDS
            reinterpret_cast<uint4*>(hb)[w4] = v;
        unsigned int ws_[4] = {v.x, v.y, v.z, v.w};
#pragma unroll
        for (int k = 0; k < 4; ++k) {
            const int   w  = w4 * 4 + k;
            const float lo = (float)(ws_[k] & 0xFFFFu);
            const float hi = (float)(ws_[k] >> 16);
            const int   i  = w >> 7;
            const int   j0 = (w & 127) << 1;
            const float fi = (float)i;
            {   float d = (float)(i - j0), d2 = d * d;
                s_con += lo * d2;
                s_dis += lo * fabsf(d);
                s_hom += lo / (1.0f + d2);
                s_i   += lo * fi;
                s_ii  += lo * fi * fi;
                s_ij  += lo * fi * (float)j0;
            }
            {   float d = (float)(i - j0 - 1), d2 = d * d;
                s_con += hi * d2;
                s_dis += hi * fabsf(d);
                s_hom += hi / (1.0f + d2);
                s_i   += hi * fi;
                s_ii  += hi * fi * fi;
                s_ij  += hi * fi * (float)(j0 + 1);
            }
        }
    }

    {
        float vals[6] = {s_con, s_dis, s_hom, s_i, s_ii, s_ij};
        const int lane = t & 63;
        const int wv   = t >> 6;
#pragma unroll
        for (int q = 0; q < 6; ++q) {
            float v = wave_red(vals[q]);
            if (lane == 0) red[wv][q] = v;
        }
        __syncthreads();
        if (t == 0) {
#pragma unroll
            for (int q = 0; q < 6; ++q) {
                float a = 0.f;
                for (int w2 = 0; w2 < 16; ++w2) a += red[w2][q];
                moments[bid * 8 + q] = a;
            }
        }
    }

    __threadfence();
    grid.sync();

    // ---- phase 2: energy partial for words [sl*4096, sl*4096+4096) --------
    {
        const unsigned int* __restrict__ hib = hist + (size_t)img * S * WORDS;
        const int w4 = sl * (WPS / 4) + t;        // uint4 index, one per thread
        unsigned int a0 = 0, a1 = 0, a2 = 0, a3 = 0, a4 = 0, a5 = 0, a6 = 0, a7 = 0;
#pragma unroll
        for (int s2 = 0; s2 < S; ++s2) {
            uint4 v;
            if (s2 == sl)
                v = reinterpret_cast<const uint4*>(sh)[w4];
            else
                v = reinterpret_cast<const uint4*>(hib + (size_t)s2 * WORDS)[w4];
            a0 += v.x & 0xFFFFu;  a1 += v.x >> 16;
            a2 += v.y & 0xFFFFu;  a3 += v.y >> 16;
            a4 += v.z & 0xFFFFu;  a5 += v.z >> 16;
            a6 += v.w & 0xFFFFu;  a7 += v.w >> 16;
        }
        float q2 = (float)a0 * (float)a0 + (float)a1 * (float)a1
                 + (float)a2 * (float)a2 + (float)a3 * (float)a3
                 + (float)a4 * (float)a4 + (float)a5 * (float)a5
                 + (float)a6 * (float)a6 + (float)a7 * (float)a7;
        float v = wave_red(q2);
        if ((t & 63) == 0) red2[t >> 6] = v;
        __syncthreads();
        if (t == 0) {
            float a = 0.f;
            for (int w2 = 0; w2 < 16; ++w2) a += red2[w2];
            q2part[bid] = a;
        }
    }

    __threadfence();
    grid.sync();

    // ---- phase 3: finalize (block 0, one thread per image) ----------------
    if (bid == 0 && t < NIMG) {
        float m[6] = {0.f, 0.f, 0.f, 0.f, 0.f, 0.f};
        float q2 = 0.f;
        for (int s2 = 0; s2 < S; ++s2) {
#pragma unroll
            for (int q = 0; q < 6; ++q)
                m[q] += moments[(t * S + s2) * 8 + q];
            q2 += q2part[t * S + s2];
        }
        const float inv = 1.0f / SUMQ;
        float contrast = m[0] * inv;
        float dissim   = m[1] * inv;
        float homog    = m[2] * inv;
        float energy   = sqrtf(q2) * inv;
        float mu       = m[3] * inv;
        float var      = m[4] * inv - mu * mu;    // var_i == var_j (Q symmetric)
        float cov      = m[5] * inv - mu * mu;
        float corr     = (var < 1e-15f) ? 1.0f : (cov / var);

        out[t * 5 + 0] = contrast;
        out[t * 5 + 1] = dissim;
        out[t * 5 + 2] = homog;
        out[t * 5 + 3] = energy;
        out[t * 5 + 4] = corr;
    }
}

extern "C" void kernel_launch(void* const* d_in, const int* in_sizes, int n_in,
                              void* d_out, int out_size, void* d_ws, size_t ws_size,
                              hipStream_t stream) {
    const float* x = (const float*)d_in[0];
    float* out = (float*)d_out;

    // ws layout: [hist: 256*32768 u32 = 32 MiB][moments: 256*8 f32][q2part: 256 f32]
    unsigned int* hist = (unsigned int*)d_ws;
    float* moments = (float*)((char*)d_ws + (size_t)NIMG * S * WORDS * 4);
    float* q2part  = moments + NIMG * S * 8;

    void* args[] = {(void*)&x, (void*)&hist, (void*)&moments, (void*)&q2part,
                    (void*)&out};
    hipLaunchCooperativeKernel((const void*)glcm_fused, dim3(NIMG * S),
                               dim3(1024), args, 0, stream);
}

// Round 5
// 33.190 us; speedup vs baseline: 6.4957x; 6.4957x over previous
//
#include <hip/hip_runtime.h>

constexpr int NIMG   = 32;
constexpr int W      = 512;
constexpr int S      = 8;                       // row-slices per image
constexpr int ROWS   = W / S;                   // 64 rows per slice
constexpr int HW_C   = 32896;                   // compact triangle halfwords = 256*257/2
constexpr int WORDS_C = HW_C / 2;               // 16448 u32 words (64.25 KB LDS)
constexpr int U4_C   = WORDS_C / 4;             // 4112 uint4 per slice histogram
constexpr int K2     = 16;                      // phase-2 chunks per image
constexpr int U4_PC  = U4_C / K2;               // 257 uint4 per chunk
constexpr float SUMQ = 2.0f * 511.0f * 512.0f;  // sum of symmetrized histogram

// ---------------------------------------------------------------------------
// canonical triangle insert: pair (a,b) -> cell (d=|a-b|, i=min(a,b))
// halfword addr h = d*(513-d)/2 + i  (diagonal-major compact upper triangle)
// ONE atomic per pair (symmetrization is analytic downstream).
// u16 safety: a slice has 64*511 = 32704 pairs total < 65536, so no cell
// can overflow even if every pair hits the same cell.
// ---------------------------------------------------------------------------
__device__ __forceinline__ void tri_add(unsigned int* sh, int a, int b) {
    int d = (a > b) ? (a - b) : (b - a);
    int m = (a < b) ? a : b;
    int h = ((d * (513 - d)) >> 1) + m;
    atomicAdd(&sh[h >> 1], 1u << ((h & 1) << 4));
}

__device__ __forceinline__ int quant(float v) {
    int q = (int)(v * 256.0f);                  // trunc toward zero == astype(int32)
    return min(255, max(0, q));
}

__device__ __forceinline__ float wave_red(float v) {
#pragma unroll
    for (int off = 32; off; off >>= 1) v += __shfl_down(v, off);
    return v;
}

// ---------------------------------------------------------------------------
// K1: one block per (image, slice). Pure histogram: build compact triangle
// GLCM of the slice in 64.25 KB LDS (u16 packed), write to exclusive global
// region. Also re-zeroes the phase-2 tickets (blocks 0..31) each call.
// ---------------------------------------------------------------------------
__global__ void __launch_bounds__(1024)
glcm_hist(const float* __restrict__ x, uint4* __restrict__ hist,
          unsigned int* __restrict__ tickets) {
    __shared__ unsigned int sh[WORDS_C];
    const int t   = threadIdx.x;
    const int bid = blockIdx.x;

    if (bid < NIMG && t == 0) tickets[bid] = 0;   // reset for this call's K2

    uint4* sh4 = reinterpret_cast<uint4*>(sh);
    for (int g = t; g < U4_C; g += 1024) sh4[g] = uint4{0u, 0u, 0u, 0u};
    __syncthreads();

    const float* __restrict__ xb = x + (size_t)bid * ROWS * W;
    const int nf4 = ROWS * (W / 4);               // 8192 float4s per slice

    for (int f = t; f < nf4; f += 1024) {
        float4 v = reinterpret_cast<const float4*>(xb)[f];
        int b0 = quant(v.x);
        int b1 = quant(v.y);
        int b2 = quant(v.z);
        int b3 = quant(v.w);
        tri_add(sh, b0, b1);
        tri_add(sh, b1, b2);
        tri_add(sh, b2, b3);
        if ((f & (W / 4 - 1)) != (W / 4 - 1)) {   // not last float4 of its row
            int b4 = quant(xb[f * 4 + 4]);
            tri_add(sh, b3, b4);
        }
    }
    __syncthreads();

    uint4* __restrict__ hb = hist + (size_t)bid * U4_C;
    for (int g = t; g < U4_C; g += 1024) hb[g] = sh4[g];
}

// ---------------------------------------------------------------------------
// K2: grid = NIMG*K2 blocks. Block (img,chunk) sums its 257-uint4 range across
// the image's 8 slice histograms, recovers (d,i) per cell, accumulates all 7
// feature sums, block-reduces, writes partials; the last-arriving block per
// image (atomic ticket) sums partials in fixed order and emits the features.
//
// Cell (d,i), j=i+d, count c (summed over slices). Full-matrix identities:
//   contrast:  sum Q*(i-j)^2      = 2*sum c*d^2
//   dissim:    sum Q*|i-j|        = 2*sum c*d
//   homog:     sum Q/(1+(i-j)^2)  = 2*sum c/(1+d^2)    (diag consistent)
//   sum Q*i                       =   sum c*(i+j)
//   sum Q*i^2                     =   sum c*(i^2+j^2)
//   sum Q*i*j                     = 2*sum c*i*j
//   sum Q^2                       = 2*sum w*c^2, w=2 on diagonal (d==0) else 1
// ---------------------------------------------------------------------------
__global__ void __launch_bounds__(256)
glcm_feat(const uint4* __restrict__ hist, float* __restrict__ part,
          unsigned int* __restrict__ tickets, float* __restrict__ out) {
    const int img   = blockIdx.x >> 4;
    const int chunk = blockIdx.x & 15;
    const uint4* __restrict__ hb = hist + (size_t)img * S * U4_C;

    float s_con = 0.f, s_dis = 0.f, s_hom = 0.f;
    float s_i = 0.f, s_ii = 0.f, s_ij = 0.f, s_q2 = 0.f;

    for (int g = threadIdx.x; g < U4_PC; g += 256) {
        const int g_abs = chunk * U4_PC + g;

        unsigned int c0 = 0, c1 = 0, c2 = 0, c3 = 0, c4 = 0, c5 = 0, c6 = 0, c7 = 0;
#pragma unroll
        for (int s = 0; s < S; ++s) {
            uint4 v = hb[(size_t)s * U4_C + g_abs];
            c0 += v.x & 0xFFFFu;  c1 += v.x >> 16;
            c2 += v.y & 0xFFFFu;  c3 += v.y >> 16;
            c4 += v.z & 0xFFFFu;  c5 += v.z >> 16;
            c6 += v.w & 0xFFFFu;  c7 += v.w >> 16;
        }
        unsigned int cc[8] = {c0, c1, c2, c3, c4, c5, c6, c7};

        // invert h0 = 8*g_abs -> (d,i):  off(d) = d*(513-d)/2 <= h0 < off(d+1)
        const int h0 = g_abs << 3;
        int d = (int)((513.0f - sqrtf((float)(263169 - 8 * h0))) * 0.5f);
        while ((d * (513 - d)) / 2 > h0) --d;               // exact fixup
        while (((d + 1) * (512 - d)) / 2 <= h0) ++d;
        int i = h0 - (d * (513 - d)) / 2;

        const float wq = (g_abs < 32) ? 2.0f : 1.0f;        // diagonal cells
#pragma unroll
        for (int k = 0; k < 8; ++k) {
            float fc = (float)cc[k];
            float fd = (float)d;
            float fi = (float)i;
            float fj = fi + fd;
            s_con += fc * fd * fd;
            s_dis += fc * fd;
            s_hom += fc / (1.0f + fd * fd);
            s_i   += fc * (fi + fj);
            s_ii  += fc * (fi * fi + fj * fj);
            s_ij  += fc * fi * fj;
            s_q2  += wq * fc * fc;
            if (++i == 256 - d) { ++d; i = 0; }             // next diagonal
        }
    }

    // block reduction of the 7 sums
    float vals[7] = {s_con, s_dis, s_hom, s_i, s_ii, s_ij, s_q2};
    __shared__ float red[4][7];
    const int lane = threadIdx.x & 63;
    const int wv   = threadIdx.x >> 6;
#pragma unroll
    for (int q = 0; q < 7; ++q) {
        float v = wave_red(vals[q]);
        if (lane == 0) red[wv][q] = v;
    }
    __syncthreads();

    if (threadIdx.x == 0) {
        float* p = part + (size_t)(img * K2 + chunk) * 8;
#pragma unroll
        for (int q = 0; q < 7; ++q)
            p[q] = red[0][q] + red[1][q] + red[2][q] + red[3][q];

        __threadfence();                                    // release partials
        unsigned int prev = atomicAdd(&tickets[img], 1u);
        if (prev == K2 - 1) {                               // last block: finalize
            __threadfence();                                // acquire partials
            float m[7] = {0.f, 0.f, 0.f, 0.f, 0.f, 0.f, 0.f};
            for (int c = 0; c < K2; ++c) {                  // fixed order: deterministic
                const float* q = part + (size_t)(img * K2 + c) * 8;
#pragma unroll
                for (int k = 0; k < 7; ++k) m[k] += q[k];
            }
            const float inv = 1.0f / SUMQ;
            float contrast = 2.0f * m[0] * inv;
            float dissim   = 2.0f * m[1] * inv;
            float homog    = 2.0f * m[2] * inv;
            float mu       = m[3] * inv;
            float var      = m[4] * inv - mu * mu;          // var_i == var_j
            float cov      = 2.0f * m[5] * inv - mu * mu;
            float energy   = sqrtf(2.0f * m[6]) * inv;
            float corr     = (var < 1e-15f) ? 1.0f : (cov / var);

            out[img * 5 + 0] = contrast;
            out[img * 5 + 1] = dissim;
            out[img * 5 + 2] = homog;
            out[img * 5 + 3] = energy;
            out[img * 5 + 4] = corr;
        }
    }
}

extern "C" void kernel_launch(void* const* d_in, const int* in_sizes, int n_in,
                              void* d_out, int out_size, void* d_ws, size_t ws_size,
                              hipStream_t stream) {
    const float* x = (const float*)d_in[0];
    float* out = (float*)d_out;

    // ws layout: [hist: 256 * 4112 uint4 = 16.84 MB][part: 32*16*8 f32][tickets: 32 u32]
    uint4* hist = (uint4*)d_ws;
    float* part = (float*)((char*)d_ws + (size_t)NIMG * S * U4_C * sizeof(uint4));
    unsigned int* tickets = (unsigned int*)(part + (size_t)NIMG * K2 * 8);

    glcm_hist<<<NIMG * S, 1024, 0, stream>>>(x, hist, tickets);
    glcm_feat<<<NIMG * K2, 256, 0, stream>>>(hist, part, tickets, out);
}